// Round 3
// baseline (220.714 us; speedup 1.0000x reference)
//
#include <hip/hip_runtime.h>
#include <stdint.h>

// PointNet Feature Propagation, MI355X.
//  K0: W f32 -> W1b bf16 [256][64], W2b bf16 [256][256]
//  K1: exact f32 3-NN + inverse-distance weights -> idxw [B][N][8]
//  K2: Zt[b][s][o] bf16 = W2 @ p2  (MFMA, LDS-transpose epilogue)
//  K3a: acc = W1@p1 (MFMA) + gather(Zt); XCD-affine batch mapping; y fragment-native
//  K3b: reduce partials -> per-channel scale/bias
//  K3c: register-decode y chunks, BN+ReLU, coalesced f32 out

#define B_   16
#define N_   4096
#define S_   1024
#define D1_  64
#define D2_  256
#define OC_  256

typedef __attribute__((ext_vector_type(8))) short bf16x8;
typedef __attribute__((ext_vector_type(4))) float f32x4;

// workspace layout (bytes)
#define IDXW_OFF 0u            // 2 MB
#define ZT_OFF   2097152u      // 8 MB
#define Y_OFF    10485760u     // 32 MB
#define PART_OFF 44040192u     // 2048*512*4 = 4 MB
#define SB_OFF   48234496u     // 2 KB
#define W1B_OFF  48236544u     // 32 KB
#define W2B_OFF  48269312u     // 128 KB
#define WS_NEED  48400384u

__device__ __forceinline__ uint16_t f2bf(float f) {
    union { float f; uint32_t u; } v; v.f = f;
    uint32_t r = v.u + 0x7FFFu + ((v.u >> 16) & 1u);   // RNE
    return (uint16_t)(r >> 16);
}
__device__ __forceinline__ float bf2f(uint32_t h) {
    union { uint32_t u; float f; } v; v.u = h << 16;
    return v.f;
}

// ---------------- K0 ----------------
__global__ void k0_prep(const float* __restrict__ W,
                        uint16_t* __restrict__ w1b, uint16_t* __restrict__ w2b) {
    int e = blockIdx.x * 256 + threadIdx.x;
    if (e >= OC_ * 320) return;
    int o = e / 320, c = e % 320;
    uint16_t b = f2bf(W[e]);
    if (c < 64) w1b[o * 64 + c] = b;
    else        w2b[o * 256 + (c - 64)] = b;
}

// ---------------- K1: three_nn ----------------
#define INSERT(d, sidx, d0, d1, d2, i0, i1, i2) do {                      \
    bool ca = (d) < (d2); bool cb = (d) < (d1); bool cc = (d) < (d0);     \
    float _n1 = __builtin_amdgcn_fmed3f((d), (d0), (d1));                 \
    float _n2 = __builtin_amdgcn_fmed3f((d), (d1), (d2));                 \
    int _j2 = cb ? (i1) : (ca ? (sidx) : (i2));                           \
    int _j1 = cc ? (i0) : (cb ? (sidx) : (i1));                           \
    i0 = cc ? (sidx) : (i0);                                              \
    d0 = fminf((d), (d0)); d1 = _n1; d2 = _n2; i1 = _j1; i2 = _j2;        \
} while (0)

__global__ void k1_threenn(const float* __restrict__ xyz1,
                           const float* __restrict__ xyz2,
                           int* __restrict__ idxw) {
    __shared__ float4 pts[4 * 257];
    int b  = blockIdx.y;
    int n0 = blockIdx.x * 128;
    int t  = threadIdx.x;

    for (int s = t; s < S_; s += 256) {
        const float* p = xyz2 + ((size_t)b * S_ + s) * 3;
        pts[(s >> 8) * 257 + (s & 255)] = make_float4(p[0], p[1], p[2], 0.f);
    }
    __syncthreads();

    int chunk = t & 3, nidx = t >> 2;
    int nA = n0 + nidx, nB = nA + 64;
    const float* q1 = xyz1 + ((size_t)b * N_ + nA) * 3;
    const float* q2 = xyz1 + ((size_t)b * N_ + nB) * 3;
    float ax = q1[0], ay = q1[1], az = q1[2];
    float bx = q2[0], by = q2[1], bz = q2[2];

    float A0 = 3.4e38f, A1 = 3.4e38f, A2 = 3.4e38f; int Ai0 = 0, Ai1 = 0, Ai2 = 0;
    float B0 = 3.4e38f, B1 = 3.4e38f, B2 = 3.4e38f; int Bi0 = 0, Bi1 = 0, Bi2 = 0;

    const float4* base = pts + chunk * 257;
    int sbase = chunk * 256;
    #pragma unroll 4
    for (int j = 0; j < 256; j++) {
        float4 q = base[j];
        int s = sbase + j;
        float dx = ax - q.x, dy = ay - q.y, dz = az - q.z;
        float dA = fmaf(dz, dz, fmaf(dy, dy, dx * dx));
        dx = bx - q.x; dy = by - q.y; dz = bz - q.z;
        float dB = fmaf(dz, dz, fmaf(dy, dy, dx * dx));
        INSERT(dA, s, A0, A1, A2, Ai0, Ai1, Ai2);
        INSERT(dB, s, B0, B1, B2, Bi0, Bi1, Bi2);
    }
    #pragma unroll
    for (int m = 1; m <= 2; m <<= 1) {
        float e0 = __shfl_xor(A0, m), e1 = __shfl_xor(A1, m), e2 = __shfl_xor(A2, m);
        int   g0 = __shfl_xor(Ai0, m), g1 = __shfl_xor(Ai1, m), g2 = __shfl_xor(Ai2, m);
        INSERT(e0, g0, A0, A1, A2, Ai0, Ai1, Ai2);
        INSERT(e1, g1, A0, A1, A2, Ai0, Ai1, Ai2);
        INSERT(e2, g2, A0, A1, A2, Ai0, Ai1, Ai2);
        e0 = __shfl_xor(B0, m); e1 = __shfl_xor(B1, m); e2 = __shfl_xor(B2, m);
        g0 = __shfl_xor(Bi0, m); g1 = __shfl_xor(Bi1, m); g2 = __shfl_xor(Bi2, m);
        INSERT(e0, g0, B0, B1, B2, Bi0, Bi1, Bi2);
        INSERT(e1, g1, B0, B1, B2, Bi0, Bi1, Bi2);
        INSERT(e2, g2, B0, B1, B2, Bi0, Bi1, Bi2);
    }
    if (chunk == 0) {
        float* fw = (float*)idxw;
        {
            float r0 = 1.0f / (A0 + 1e-8f), r1 = 1.0f / (A1 + 1e-8f), r2 = 1.0f / (A2 + 1e-8f);
            float rs = r0 + r1 + r2;
            int base1 = (b * N_ + nA) * 8;
            idxw[base1 + 0] = Ai0; idxw[base1 + 1] = Ai1; idxw[base1 + 2] = Ai2;
            fw[base1 + 4] = r0 / rs; fw[base1 + 5] = r1 / rs; fw[base1 + 6] = r2 / rs;
        }
        {
            float r0 = 1.0f / (B0 + 1e-8f), r1 = 1.0f / (B1 + 1e-8f), r2 = 1.0f / (B2 + 1e-8f);
            float rs = r0 + r1 + r2;
            int base2 = (b * N_ + nB) * 8;
            idxw[base2 + 0] = Bi0; idxw[base2 + 1] = Bi1; idxw[base2 + 2] = Bi2;
            fw[base2 + 4] = r0 / rs; fw[base2 + 5] = r1 / rs; fw[base2 + 6] = r2 / rs;
        }
    }
}

// ---------------- K2: Zt bf16 [b][s][o] ----------------
__global__ void k2_z(const float* __restrict__ p2, const uint16_t* __restrict__ w2b,
                     uint16_t* __restrict__ zt) {
    __shared__ char smem[40960];
    uint16_t* a_t = (uint16_t*)smem;            // [64 s][64 c], 128B rows, swz <<4
    uint16_t* w_t = (uint16_t*)(smem + 8192);   // [256 o][64 c]
    int b = blockIdx.y, s0 = blockIdx.x * 64;
    int t = threadIdx.x, l = t & 63, w = t >> 6;   // 4 waves

    f32x4 acc[4][4] = {};   // [mi(s)][oj(o)]
    for (int ck = 0; ck < 4; ck++) {
        __syncthreads();
        {
            int sA = w * 16 + (l & 15);
            const float* p2b = p2 + ((size_t)b * D2_ + (size_t)ck * 64) * S_ + s0;
            #pragma unroll
            for (int j = 0; j < 8; j++) {
                int cp = (l >> 4) + 4 * j;
                float lo = p2b[(size_t)(2 * cp) * S_ + sA];
                float hi = p2b[(size_t)(2 * cp + 1) * S_ + sA];
                uint32_t pk = (uint32_t)f2bf(lo) | ((uint32_t)f2bf(hi) << 16);
                int bo = (cp * 4) ^ ((sA & 7) << 4);
                *(uint32_t*)((char*)a_t + sA * 128 + bo) = pk;
            }
        }
        {
            int wp = t & 31, orow0 = t >> 5;
            #pragma unroll 4
            for (int jj = 0; jj < 32; jj++) {
                int o = orow0 + 8 * jj;
                uint32_t v = *(const uint32_t*)(w2b + (size_t)o * 256 + ck * 64 + 2 * wp);
                int bo = (wp * 4) ^ ((o & 7) << 4);
                *(uint32_t*)((char*)w_t + o * 128 + bo) = v;
            }
        }
        __syncthreads();
        #pragma unroll
        for (int ks = 0; ks < 2; ks++) {
            bf16x8 a[4], bb[4];
            int co = ks * 32 + (l >> 4) * 8;
            #pragma unroll
            for (int mi = 0; mi < 4; mi++) {
                int s = mi * 16 + (l & 15);
                int bo = (co * 2) ^ ((s & 7) << 4);
                a[mi] = *(const bf16x8*)((const char*)a_t + s * 128 + bo);
            }
            #pragma unroll
            for (int oj = 0; oj < 4; oj++) {
                int o = w * 64 + oj * 16 + (l & 15);
                int bo = (co * 2) ^ ((o & 7) << 4);
                bb[oj] = *(const bf16x8*)((const char*)w_t + o * 128 + bo);
            }
            #pragma unroll
            for (int mi = 0; mi < 4; mi++)
                #pragma unroll
                for (int oj = 0; oj < 4; oj++)
                    acc[mi][oj] = __builtin_amdgcn_mfma_f32_16x16x32_bf16(
                        a[mi], bb[oj], acc[mi][oj], 0, 0, 0);
        }
    }
    __syncthreads();
    char* tz = smem;   // [64 s][512 B], swz <<5
    #pragma unroll
    for (int mi = 0; mi < 4; mi++)
        #pragma unroll
        for (int oj = 0; oj < 4; oj++)
            #pragma unroll
            for (int r = 0; r < 4; r++) {
                int sl = mi * 16 + (l >> 4) * 4 + r;
                int o  = w * 64 + oj * 16 + (l & 15);
                *(uint16_t*)(tz + sl * 512 + ((o * 2) ^ ((sl & 7) << 5))) = f2bf(acc[mi][oj][r]);
            }
    __syncthreads();
    uint16_t* ztb = zt + ((size_t)b * S_ + s0) * 256;
    #pragma unroll
    for (int k = 0; k < 16; k++) {
        int sl = w * 16 + k;
        #pragma unroll
        for (int h = 0; h < 2; h++) {
            uint32_t v = *(uint32_t*)(tz + sl * 512 + ((h * 256 + l * 4) ^ ((sl & 7) << 5)));
            *(uint32_t*)(ztb + (size_t)sl * 256 + h * 128 + l * 2) = v;
        }
    }
}

// ---------------- K3a: XCD-affine, 32n x 256o tiles ----------------
__global__ void __launch_bounds__(256, 8)
k3a(const float* __restrict__ p1, const uint16_t* __restrict__ w1b,
    const int* __restrict__ idxw, const uint16_t* __restrict__ zt,
    uint16_t* __restrict__ y, float* __restrict__ partials) {
    int i = blockIdx.x;                  // 2048
    int xcd = i & 7, slot = i >> 3;      // dispatch round-robins XCDs (heuristic)
    int b = xcd * 2 + (slot >> 7);       // each XCD owns 2 batches -> 1MB Zt slice in its L2
    int n0 = (slot & 127) * 32;
    int t = threadIdx.x, l = t & 63, w = t >> 6;   // 4 waves
    int oW = w * 64;
    __shared__ uint16_t pt[32 * 64];     // [n][c] bf16, 128B rows, swz <<4

    // stage p1 tile [32n][64c] transposed to bf16
    {
        int nn = t & 31;
        const float* p1b = p1 + (size_t)b * D1_ * N_ + n0;
        #pragma unroll
        for (int j = 0; j < 4; j++) {
            int cp = (t >> 5) + 8 * j;
            float lo = p1b[(size_t)(2 * cp) * N_ + nn];
            float hi = p1b[(size_t)(2 * cp + 1) * N_ + nn];
            uint32_t pk = (uint32_t)f2bf(lo) | ((uint32_t)f2bf(hi) << 16);
            int bo = (cp * 4) ^ ((nn & 7) << 4);
            *(uint32_t*)((char*)pt + nn * 128 + bo) = pk;
        }
    }
    bf16x8 af[2][4];
    #pragma unroll
    for (int ks = 0; ks < 2; ks++)
        #pragma unroll
        for (int mi = 0; mi < 4; mi++) {
            int o = oW + mi * 16 + (l & 15);
            int k = ks * 32 + (l >> 4) * 8;
            af[ks][mi] = *(const bf16x8*)(w1b + (size_t)o * 64 + k);
        }
    f32x4 acc[4][2] = {};   // [mi(o)][bj(n)]
    __syncthreads();
    #pragma unroll
    for (int ks = 0; ks < 2; ks++) {
        bf16x8 bf[2];
        int co = ks * 32 + (l >> 4) * 8;
        #pragma unroll
        for (int bj = 0; bj < 2; bj++) {
            int nn = bj * 16 + (l & 15);
            int bo = (co * 2) ^ ((nn & 7) << 4);
            bf[bj] = *(const bf16x8*)((const char*)pt + nn * 128 + bo);
        }
        #pragma unroll
        for (int mi = 0; mi < 4; mi++)
            #pragma unroll
            for (int bj = 0; bj < 2; bj++)
                acc[mi][bj] = __builtin_amdgcn_mfma_f32_16x16x32_bf16(
                    af[ks][mi], bf[bj], acc[mi][bj], 0, 0, 0);
    }
    // gather-add from bf16 Zt (L2-resident via XCD affinity)
    const uint16_t* ztb = zt + (size_t)b * S_ * 256;
    #pragma unroll
    for (int bj = 0; bj < 2; bj++) {
        int nn = n0 + bj * 16 + (l & 15);
        const int* ib = idxw + ((size_t)(b * N_ + nn)) * 8;
        int4   iv = *(const int4*)ib;
        float4 wv = *((const float4*)ib + 1);
        #pragma unroll
        for (int mi = 0; mi < 4; mi++) {
            int o = oW + mi * 16 + (l >> 4) * 4;
            uint2 z0 = *(const uint2*)(ztb + (size_t)iv.x * 256 + o);
            uint2 z1 = *(const uint2*)(ztb + (size_t)iv.y * 256 + o);
            uint2 z2 = *(const uint2*)(ztb + (size_t)iv.z * 256 + o);
            acc[mi][bj][0] += wv.x * bf2f(z0.x & 0xffff) + wv.y * bf2f(z1.x & 0xffff) + wv.z * bf2f(z2.x & 0xffff);
            acc[mi][bj][1] += wv.x * bf2f(z0.x >> 16)    + wv.y * bf2f(z1.x >> 16)    + wv.z * bf2f(z2.x >> 16);
            acc[mi][bj][2] += wv.x * bf2f(z0.y & 0xffff) + wv.y * bf2f(z1.y & 0xffff) + wv.z * bf2f(z2.y & 0xffff);
            acc[mi][bj][3] += wv.x * bf2f(z0.y >> 16)    + wv.y * bf2f(z1.y >> 16)    + wv.z * bf2f(z2.y >> 16);
        }
    }
    // BN partial sums
    float s1[4][4], s2v[4][4];
    #pragma unroll
    for (int mi = 0; mi < 4; mi++)
        #pragma unroll
        for (int r = 0; r < 4; r++) {
            float a = 0.f, q = 0.f;
            #pragma unroll
            for (int bj = 0; bj < 2; bj++) { float v = acc[mi][bj][r]; a += v; q += v * v; }
            s1[mi][r] = a; s2v[mi][r] = q;
        }
    #pragma unroll
    for (int m = 1; m <= 8; m <<= 1)
        #pragma unroll
        for (int mi = 0; mi < 4; mi++)
            #pragma unroll
            for (int r = 0; r < 4; r++) {
                s1[mi][r]  += __shfl_xor(s1[mi][r], m);
                s2v[mi][r] += __shfl_xor(s2v[mi][r], m);
            }
    if ((l & 15) == 0) {
        float* ps = partials + (size_t)i * 512;
        #pragma unroll
        for (int mi = 0; mi < 4; mi++)
            #pragma unroll
            for (int r = 0; r < 4; r++) {
                int o = oW + mi * 16 + (l >> 4) * 4 + r;
                ps[o * 2 + 0] = s1[mi][r];
                ps[o * 2 + 1] = s2v[mi][r];
            }
    }
    // store y: fragment-native, block chunk = 16KB contiguous
    uint16_t* yb = y + (size_t)i * 8192 + w * 2048 + l;
    #pragma unroll
    for (int mi = 0; mi < 4; mi++)
        #pragma unroll
        for (int bj = 0; bj < 2; bj++)
            #pragma unroll
            for (int r = 0; r < 4; r++)
                yb[(size_t)(mi * 8 + bj * 4 + r) * 64] = f2bf(acc[mi][bj][r]);
}

// ---------------- K3b ----------------
__global__ void k3b(const float* __restrict__ partials, const float* __restrict__ gamma,
                    const float* __restrict__ beta, float* __restrict__ sb) {
    int o = blockIdx.x, t = threadIdx.x;
    float a = 0.f, q = 0.f;
    for (int sl = t; sl < 2048; sl += 256) {
        const float* p = partials + (size_t)sl * 512 + o * 2;
        a += p[0]; q += p[1];
    }
    #pragma unroll
    for (int m = 1; m < 64; m <<= 1) { a += __shfl_xor(a, m); q += __shfl_xor(q, m); }
    __shared__ float red[8];
    int w = t >> 6, l = t & 63;
    if (l == 0) { red[w * 2] = a; red[w * 2 + 1] = q; }
    __syncthreads();
    if (t == 0) {
        float A = red[0] + red[2] + red[4] + red[6];
        float Q = red[1] + red[3] + red[5] + red[7];
        float mean = A / 65536.0f;
        float var  = Q / 65536.0f - mean * mean;
        float scale = gamma[o] / sqrtf(var + 1e-5f);
        sb[o * 2] = scale;
        sb[o * 2 + 1] = beta[o] - mean * scale;
    }
}

// ---------------- K3c: register decode, BN+ReLU, no LDS ----------------
__global__ void k3c(const uint16_t* __restrict__ y, const float* __restrict__ sb,
                    float* __restrict__ out) {
    int i = blockIdx.x;                 // 2048, same mapping as k3a
    int b = (i & 7) * 2 + ((i >> 3) >> 7);
    int n0 = ((i >> 3) & 127) * 32;
    int u = threadIdx.x;
    const uint4* yp = (const uint4*)(y + (size_t)i * 8192);
    int f  = (u >> 3) & 31;             // frag index: mi*8 + bj*4 + r
    int mi = f >> 3, bj = (f >> 2) & 1, r = f & 3;
    int l0 = (u * 8) & 63;
    int n  = bj * 16 + (l0 & 15);       // 8 consecutive n from here
    int obase = mi * 16 + ((l0 >> 4) << 2) + r;
    #pragma unroll
    for (int j = 0; j < 4; j++) {       // w = j
        uint4 v = yp[u + 256 * j];
        int o = j * 64 + obase;
        float scale = sb[o * 2], bias = sb[o * 2 + 1];
        float4 r0, r1;
        r0.x = fmaxf(0.f, fmaf(bf2f(v.x & 0xffff), scale, bias));
        r0.y = fmaxf(0.f, fmaf(bf2f(v.x >> 16),    scale, bias));
        r0.z = fmaxf(0.f, fmaf(bf2f(v.y & 0xffff), scale, bias));
        r0.w = fmaxf(0.f, fmaf(bf2f(v.y >> 16),    scale, bias));
        r1.x = fmaxf(0.f, fmaf(bf2f(v.z & 0xffff), scale, bias));
        r1.y = fmaxf(0.f, fmaf(bf2f(v.z >> 16),    scale, bias));
        r1.z = fmaxf(0.f, fmaf(bf2f(v.w & 0xffff), scale, bias));
        r1.w = fmaxf(0.f, fmaf(bf2f(v.w >> 16),    scale, bias));
        float* op = out + ((size_t)b * OC_ + o) * N_ + n0 + n;
        *(float4*)op = r0;
        *(float4*)(op + 4) = r1;
    }
}

extern "C" void kernel_launch(void* const* d_in, const int* in_sizes, int n_in,
                              void* d_out, int out_size, void* d_ws, size_t ws_size,
                              hipStream_t stream) {
    const float* xyz1  = (const float*)d_in[0];
    const float* xyz2  = (const float*)d_in[1];
    const float* p1    = (const float*)d_in[2];
    const float* p2    = (const float*)d_in[3];
    const float* W     = (const float*)d_in[4];
    const float* gamma = (const float*)d_in[5];
    const float* beta  = (const float*)d_in[6];
    float* out = (float*)d_out;
    char* ws = (char*)d_ws;
    if (ws_size < (size_t)WS_NEED) return;

    int*      idxw     = (int*)(ws + IDXW_OFF);
    uint16_t* zt       = (uint16_t*)(ws + ZT_OFF);
    uint16_t* y        = (uint16_t*)(ws + Y_OFF);
    float*    partials = (float*)(ws + PART_OFF);
    float*    sb       = (float*)(ws + SB_OFF);
    uint16_t* w1b      = (uint16_t*)(ws + W1B_OFF);
    uint16_t* w2b      = (uint16_t*)(ws + W2B_OFF);

    hipLaunchKernelGGL(k0_prep,    dim3(320),    dim3(256), 0, stream, W, w1b, w2b);
    hipLaunchKernelGGL(k1_threenn, dim3(32, 16), dim3(256), 0, stream, xyz1, xyz2, idxw);
    hipLaunchKernelGGL(k2_z,       dim3(16, 16), dim3(256), 0, stream, p2, w2b, zt);
    hipLaunchKernelGGL(k3a,        dim3(2048),   dim3(256), 0, stream, p1, w1b, idxw, zt, y, partials);
    hipLaunchKernelGGL(k3b,        dim3(256),    dim3(256), 0, stream, partials, gamma, beta, sb);
    hipLaunchKernelGGL(k3c,        dim3(2048),   dim3(256), 0, stream, y, sb, out);
}

// Round 5
// 146.443 us; speedup vs baseline: 1.5072x; 1.5072x over previous
//
#include <hip/hip_runtime.h>
#include <stdint.h>

// PointNet Feature Propagation, MI355X.
//  K0 : W f32 -> w1b bf16 [256][64], w2b bf16 [256][256]
//  K1 : exact f32 3-NN + inverse-distance weights -> idxw [B][N][8]
//  K2 : ztb = W2 @ p2, bf16, o-blocked [b][og16][s1024][16o]
//  K2b: y1 = W1 @ p1, bf16, o-blocked [b][og16][n4096][16o]
//  K3a: y = y1 + sum_k w_k * ztb[idx_k]  (gather from LDS-staged Zt slice)
//       -> d_out f32 [b][o][n] (pre-BN) + BN partials
//  K3b: partials -> per-channel scale/bias
//  K3c: in-place BN+ReLU on d_out

#define B_   16
#define N_   4096
#define S_   1024
#define D1_  64
#define D2_  256
#define OC_  256

typedef __attribute__((ext_vector_type(8))) short bf16x8;
typedef __attribute__((ext_vector_type(4))) float f32x4;
typedef __attribute__((ext_vector_type(4))) unsigned int u32x4;
typedef __attribute__((ext_vector_type(2))) unsigned int u32x2;

// workspace layout (bytes)
#define IDXW_OFF 0u           // 16*4096*8*4 = 2 MB
#define ZTB_OFF  2097152u     // 16*16*1024*16*2 = 8 MB
#define Y1_OFF   10485760u    // 16*16*4096*16*2 = 32 MB
#define PART_OFF 44040192u    // 512*32*4 = 64 KB
#define SB_OFF   44105728u    // 2 KB
#define W1B_OFF  44107776u    // 32 KB
#define W2B_OFF  44140544u    // 128 KB
#define WS_NEED  44271616u

__device__ __forceinline__ uint16_t f2bf(float f) {
    union { float f; uint32_t u; } v; v.f = f;
    uint32_t r = v.u + 0x7FFFu + ((v.u >> 16) & 1u);   // RNE
    return (uint16_t)(r >> 16);
}
__device__ __forceinline__ float bf2f(uint32_t h) {
    union { uint32_t u; float f; } v; v.u = h << 16;
    return v.f;
}

// ---------------- K0 ----------------
__global__ void k0_prep(const float* __restrict__ W,
                        uint16_t* __restrict__ w1b, uint16_t* __restrict__ w2b) {
    int e = blockIdx.x * 256 + threadIdx.x;
    if (e >= OC_ * 320) return;
    int o = e / 320, c = e % 320;
    uint16_t b = f2bf(W[e]);
    if (c < 64) w1b[o * 64 + c] = b;
    else        w2b[o * 256 + (c - 64)] = b;
}

// ---------------- K1: three_nn ----------------
#define INSERT(d, sidx, d0, d1, d2, i0, i1, i2) do {                      \
    bool ca = (d) < (d2); bool cb = (d) < (d1); bool cc = (d) < (d0);     \
    float _n1 = __builtin_amdgcn_fmed3f((d), (d0), (d1));                 \
    float _n2 = __builtin_amdgcn_fmed3f((d), (d1), (d2));                 \
    int _j2 = cb ? (i1) : (ca ? (sidx) : (i2));                           \
    int _j1 = cc ? (i0) : (cb ? (sidx) : (i1));                           \
    i0 = cc ? (sidx) : (i0);                                              \
    d0 = fminf((d), (d0)); d1 = _n1; d2 = _n2; i1 = _j1; i2 = _j2;        \
} while (0)

__global__ void k1_threenn(const float* __restrict__ xyz1,
                           const float* __restrict__ xyz2,
                           int* __restrict__ idxw) {
    __shared__ float4 pts[4 * 257];
    int b  = blockIdx.y;
    int n0 = blockIdx.x * 128;
    int t  = threadIdx.x;

    for (int s = t; s < S_; s += 256) {
        const float* p = xyz2 + ((size_t)b * S_ + s) * 3;
        pts[(s >> 8) * 257 + (s & 255)] = make_float4(p[0], p[1], p[2], 0.f);
    }
    __syncthreads();

    int chunk = t & 3, nidx = t >> 2;
    int nA = n0 + nidx, nB = nA + 64;
    const float* q1 = xyz1 + ((size_t)b * N_ + nA) * 3;
    const float* q2 = xyz1 + ((size_t)b * N_ + nB) * 3;
    float ax = q1[0], ay = q1[1], az = q1[2];
    float bx = q2[0], by = q2[1], bz = q2[2];

    float A0 = 3.4e38f, A1 = 3.4e38f, A2 = 3.4e38f; int Ai0 = 0, Ai1 = 0, Ai2 = 0;
    float B0 = 3.4e38f, B1 = 3.4e38f, B2 = 3.4e38f; int Bi0 = 0, Bi1 = 0, Bi2 = 0;

    const float4* base = pts + chunk * 257;
    int sbase = chunk * 256;
    #pragma unroll 4
    for (int j = 0; j < 256; j++) {
        float4 q = base[j];
        int s = sbase + j;
        float dx = ax - q.x, dy = ay - q.y, dz = az - q.z;
        float dA = fmaf(dz, dz, fmaf(dy, dy, dx * dx));
        dx = bx - q.x; dy = by - q.y; dz = bz - q.z;
        float dB = fmaf(dz, dz, fmaf(dy, dy, dx * dx));
        INSERT(dA, s, A0, A1, A2, Ai0, Ai1, Ai2);
        INSERT(dB, s, B0, B1, B2, Bi0, Bi1, Bi2);
    }
    #pragma unroll
    for (int m = 1; m <= 2; m <<= 1) {
        float e0 = __shfl_xor(A0, m), e1 = __shfl_xor(A1, m), e2 = __shfl_xor(A2, m);
        int   g0 = __shfl_xor(Ai0, m), g1 = __shfl_xor(Ai1, m), g2 = __shfl_xor(Ai2, m);
        INSERT(e0, g0, A0, A1, A2, Ai0, Ai1, Ai2);
        INSERT(e1, g1, A0, A1, A2, Ai0, Ai1, Ai2);
        INSERT(e2, g2, A0, A1, A2, Ai0, Ai1, Ai2);
        e0 = __shfl_xor(B0, m); e1 = __shfl_xor(B1, m); e2 = __shfl_xor(B2, m);
        g0 = __shfl_xor(Bi0, m); g1 = __shfl_xor(Bi1, m); g2 = __shfl_xor(Bi2, m);
        INSERT(e0, g0, B0, B1, B2, Bi0, Bi1, Bi2);
        INSERT(e1, g1, B0, B1, B2, Bi0, Bi1, Bi2);
        INSERT(e2, g2, B0, B1, B2, Bi0, Bi1, Bi2);
    }
    if (chunk == 0) {
        float* fw = (float*)idxw;
        {
            float r0 = 1.0f / (A0 + 1e-8f), r1 = 1.0f / (A1 + 1e-8f), r2 = 1.0f / (A2 + 1e-8f);
            float rs = r0 + r1 + r2;
            int base1 = (b * N_ + nA) * 8;
            idxw[base1 + 0] = Ai0; idxw[base1 + 1] = Ai1; idxw[base1 + 2] = Ai2;
            fw[base1 + 4] = r0 / rs; fw[base1 + 5] = r1 / rs; fw[base1 + 6] = r2 / rs;
        }
        {
            float r0 = 1.0f / (B0 + 1e-8f), r1 = 1.0f / (B1 + 1e-8f), r2 = 1.0f / (B2 + 1e-8f);
            float rs = r0 + r1 + r2;
            int base2 = (b * N_ + nB) * 8;
            idxw[base2 + 0] = Bi0; idxw[base2 + 1] = Bi1; idxw[base2 + 2] = Bi2;
            fw[base2 + 4] = r0 / rs; fw[base2 + 5] = r1 / rs; fw[base2 + 6] = r2 / rs;
        }
    }
}

// ---------------- K2: ztb = W2@p2, o-blocked bf16 ----------------
__global__ void k2_z(const float* __restrict__ p2, const uint16_t* __restrict__ w2b,
                     uint16_t* __restrict__ ztb) {
    __shared__ char smem[40960];
    uint16_t* a_t = (uint16_t*)smem;            // [64 s][64 c], 128B rows, swz <<4
    uint16_t* w_t = (uint16_t*)(smem + 8192);   // [256 o][64 c]
    int b = blockIdx.y, s0 = blockIdx.x * 64;
    int t = threadIdx.x, l = t & 63, w = t >> 6;   // 4 waves

    f32x4 acc[4][4] = {};   // [mi(s)][oj(o)]
    for (int ck = 0; ck < 4; ck++) {
        __syncthreads();
        {
            int sA = w * 16 + (l & 15);
            const float* p2b = p2 + ((size_t)b * D2_ + (size_t)ck * 64) * S_ + s0;
            #pragma unroll
            for (int j = 0; j < 8; j++) {
                int cp = (l >> 4) + 4 * j;
                float lo = p2b[(size_t)(2 * cp) * S_ + sA];
                float hi = p2b[(size_t)(2 * cp + 1) * S_ + sA];
                uint32_t pk = (uint32_t)f2bf(lo) | ((uint32_t)f2bf(hi) << 16);
                *(uint32_t*)((char*)a_t + sA * 128 + ((cp * 4) ^ ((sA & 7) << 4))) = pk;
            }
        }
        {
            int wp = t & 31, orow0 = t >> 5;
            #pragma unroll 4
            for (int jj = 0; jj < 32; jj++) {
                int o = orow0 + 8 * jj;
                uint32_t v = *(const uint32_t*)(w2b + (size_t)o * 256 + ck * 64 + 2 * wp);
                *(uint32_t*)((char*)w_t + o * 128 + ((wp * 4) ^ ((o & 7) << 4))) = v;
            }
        }
        __syncthreads();
        #pragma unroll
        for (int ks = 0; ks < 2; ks++) {
            bf16x8 a[4], bb[4];
            int co = ks * 32 + (l >> 4) * 8;
            #pragma unroll
            for (int mi = 0; mi < 4; mi++) {
                int s = mi * 16 + (l & 15);
                a[mi] = *(const bf16x8*)((const char*)a_t + s * 128 + ((co * 2) ^ ((s & 7) << 4)));
            }
            #pragma unroll
            for (int oj = 0; oj < 4; oj++) {
                int o = w * 64 + oj * 16 + (l & 15);
                bb[oj] = *(const bf16x8*)((const char*)w_t + o * 128 + ((co * 2) ^ ((o & 7) << 4)));
            }
            #pragma unroll
            for (int mi = 0; mi < 4; mi++)
                #pragma unroll
                for (int oj = 0; oj < 4; oj++)
                    acc[mi][oj] = __builtin_amdgcn_mfma_f32_16x16x32_bf16(
                        a[mi], bb[oj], acc[mi][oj], 0, 0, 0);
        }
    }
    // transpose via LDS -> o-blocked write
    __syncthreads();
    char* tz = smem;   // [64 s][512 B], swz <<5
    #pragma unroll
    for (int mi = 0; mi < 4; mi++)
        #pragma unroll
        for (int oj = 0; oj < 4; oj++)
            #pragma unroll
            for (int r = 0; r < 4; r++) {
                int sl = mi * 16 + (l >> 4) * 4 + r;
                int o  = w * 64 + oj * 16 + (l & 15);
                *(uint16_t*)(tz + sl * 512 + ((o * 2) ^ ((sl & 7) << 5))) = f2bf(acc[mi][oj][r]);
            }
    __syncthreads();
    {
        int og = t >> 4, rr = t & 15;
        uint16_t* zb = ztb + ((size_t)(b * 16 + og) * S_ + s0) * 16;
        #pragma unroll
        for (int k = 0; k < 4; k++) {
            int s = rr * 4 + k;
            u32x4 v0 = *(u32x4*)(tz + s * 512 + ((og * 32) ^ ((s & 7) << 5)));
            u32x4 v1 = *(u32x4*)(tz + s * 512 + (((og * 32) ^ ((s & 7) << 5)) | 16));
            __builtin_nontemporal_store(v0, (u32x4*)(zb + (size_t)s * 16));
            __builtin_nontemporal_store(v1, (u32x4*)(zb + (size_t)s * 16 + 8));
        }
    }
}

// ---------------- K2b: y1 = W1@p1, o-blocked bf16 ----------------
__global__ void __launch_bounds__(256, 4)
k2b(const float* __restrict__ p1, const uint16_t* __restrict__ w1b,
    uint16_t* __restrict__ y1) {
    int i = blockIdx.x;            // 2048
    int b = i >> 7, n0 = (i & 127) * 32;
    int t = threadIdx.x, l = t & 63, w = t >> 6;
    int oW = w * 64;
    __shared__ uint16_t pt[32 * 64];   // [n][c], 128B rows, swz <<4
    {
        int nn = t & 31;
        const float* p1b = p1 + (size_t)b * D1_ * N_ + n0;
        #pragma unroll
        for (int j = 0; j < 4; j++) {
            int cp = (t >> 5) + 8 * j;
            float lo = p1b[(size_t)(2 * cp) * N_ + nn];
            float hi = p1b[(size_t)(2 * cp + 1) * N_ + nn];
            uint32_t pk = (uint32_t)f2bf(lo) | ((uint32_t)f2bf(hi) << 16);
            *(uint32_t*)((char*)pt + nn * 128 + ((cp * 4) ^ ((nn & 7) << 4))) = pk;
        }
    }
    bf16x8 af[2][4];
    #pragma unroll
    for (int ks = 0; ks < 2; ks++)
        #pragma unroll
        for (int mi = 0; mi < 4; mi++) {
            int o = oW + mi * 16 + (l & 15);
            af[ks][mi] = *(const bf16x8*)(w1b + (size_t)o * 64 + ks * 32 + (l >> 4) * 8);
        }
    f32x4 acc[4][2] = {};   // [mi(o)][bj(n)]
    __syncthreads();
    #pragma unroll
    for (int ks = 0; ks < 2; ks++) {
        bf16x8 bf[2];
        int co = ks * 32 + (l >> 4) * 8;
        #pragma unroll
        for (int bj = 0; bj < 2; bj++) {
            int nn = bj * 16 + (l & 15);
            bf[bj] = *(const bf16x8*)((const char*)pt + nn * 128 + ((co * 2) ^ ((nn & 7) << 4)));
        }
        #pragma unroll
        for (int mi = 0; mi < 4; mi++)
            #pragma unroll
            for (int bj = 0; bj < 2; bj++)
                acc[mi][bj] = __builtin_amdgcn_mfma_f32_16x16x32_bf16(
                    af[ks][mi], bf[bj], acc[mi][bj], 0, 0, 0);
    }
    // o-blocked store: [b][og][n][16], 8B/lane, 512B contiguous per inst
    #pragma unroll
    for (int mi = 0; mi < 4; mi++) {
        int og = w * 4 + mi;
        uint16_t* yb = y1 + ((size_t)(b * 16 + og)) * N_ * 16;
        #pragma unroll
        for (int bj = 0; bj < 2; bj++) {
            int n = n0 + bj * 16 + (l & 15);
            int oo = (l >> 4) * 4;
            u32x2 v;
            v.x = (uint32_t)f2bf(acc[mi][bj][0]) | ((uint32_t)f2bf(acc[mi][bj][1]) << 16);
            v.y = (uint32_t)f2bf(acc[mi][bj][2]) | ((uint32_t)f2bf(acc[mi][bj][3]) << 16);
            __builtin_nontemporal_store(v, (u32x2*)(yb + (size_t)n * 16 + oo));
        }
    }
}

// ---------------- K3a: LDS-staged gather + BN partials ----------------
__global__ void __launch_bounds__(512, 4)
k3a(const uint16_t* __restrict__ y1, const uint16_t* __restrict__ ztb,
    const int* __restrict__ idxw, float* __restrict__ yout,
    float* __restrict__ partials) {
    __shared__ char zsm[49152];          // [1024 s][48B] rows (32B used) - bank spread
    __shared__ float red[8][16][2];
    int bi = blockIdx.x;                 // 512
    int b = bi >> 5, og = (bi >> 1) & 15, nh = bi & 1;
    int u = threadIdx.x, l = u & 63, w = u >> 6;
    // stage Zt[b][og] slice: 32KB contiguous global -> padded LDS rows
    {
        const u32x4* src = (const u32x4*)(ztb + ((size_t)(b * 16 + og)) * S_ * 16);
        #pragma unroll
        for (int k = 0; k < 4; k++) {
            int g = k * 512 + u;
            u32x4 v = src[g];
            *(u32x4*)(zsm + (g >> 1) * 48 + (g & 1) * 16) = v;
        }
    }
    __syncthreads();
    int q = l >> 2, sub = l & 3;
    float s1l[4] = {0.f, 0.f, 0.f, 0.f}, s2l[4] = {0.f, 0.f, 0.f, 0.f};
    int nbase = nh * 2048 + w * 256;
    const uint16_t* y1b = y1 + ((size_t)(b * 16 + og)) * N_ * 16;
    float* yrow = yout + ((size_t)(b * OC_ + og * 16 + sub * 4)) * N_;
    for (int it = 0; it < 16; it++) {
        int n = nbase + it * 16 + q;
        u32x2 y1v = __builtin_nontemporal_load((const u32x2*)(y1b + (size_t)n * 16 + sub * 4));
        const int* ib = idxw + ((size_t)(b * N_ + n)) * 8;
        int4   iv = *(const int4*)ib;
        float4 wv = *((const float4*)ib + 1);
        u32x2 z0 = *(const u32x2*)(zsm + iv.x * 48 + sub * 8);
        u32x2 z1 = *(const u32x2*)(zsm + iv.y * 48 + sub * 8);
        u32x2 z2 = *(const u32x2*)(zsm + iv.z * 48 + sub * 8);
        float a0 = bf2f(y1v.x & 0xffff) + wv.x * bf2f(z0.x & 0xffff) + wv.y * bf2f(z1.x & 0xffff) + wv.z * bf2f(z2.x & 0xffff);
        float a1 = bf2f(y1v.x >> 16)    + wv.x * bf2f(z0.x >> 16)    + wv.y * bf2f(z1.x >> 16)    + wv.z * bf2f(z2.x >> 16);
        float a2 = bf2f(y1v.y & 0xffff) + wv.x * bf2f(z0.y & 0xffff) + wv.y * bf2f(z1.y & 0xffff) + wv.z * bf2f(z2.y & 0xffff);
        float a3 = bf2f(y1v.y >> 16)    + wv.x * bf2f(z0.y >> 16)    + wv.y * bf2f(z1.y >> 16)    + wv.z * bf2f(z2.y >> 16);
        s1l[0] += a0; s2l[0] += a0 * a0;
        s1l[1] += a1; s2l[1] += a1 * a1;
        s1l[2] += a2; s2l[2] += a2 * a2;
        s1l[3] += a3; s2l[3] += a3 * a3;
        __builtin_nontemporal_store(a0, yrow + 0 * N_ + n);
        __builtin_nontemporal_store(a1, yrow + 1 * N_ + n);
        __builtin_nontemporal_store(a2, yrow + 2 * N_ + n);
        __builtin_nontemporal_store(a3, yrow + 3 * N_ + n);
    }
    // reduce over q (lane bits 2..5)
    #pragma unroll
    for (int m = 4; m <= 32; m <<= 1)
        #pragma unroll
        for (int j = 0; j < 4; j++) {
            s1l[j] += __shfl_xor(s1l[j], m);
            s2l[j] += __shfl_xor(s2l[j], m);
        }
    if (l < 4) {
        #pragma unroll
        for (int j = 0; j < 4; j++) {
            red[w][sub * 4 + j][0] = s1l[j];
            red[w][sub * 4 + j][1] = s2l[j];
        }
    }
    __syncthreads();
    if (u < 32) {
        int oi = u >> 1, st = u & 1;
        float s = 0.f;
        #pragma unroll
        for (int ww = 0; ww < 8; ww++) s += red[ww][oi][st];
        partials[(size_t)bi * 32 + oi * 2 + st] = s;
    }
}

// ---------------- K3b ----------------
__global__ void k3b(const float* __restrict__ partials, const float* __restrict__ gamma,
                    const float* __restrict__ beta, float* __restrict__ sb) {
    int o = threadIdx.x;           // 256
    int og = o >> 4, oo = o & 15;
    float a = 0.f, q = 0.f;
    for (int t = 0; t < 32; t++) {
        int bb = t >> 1, nh = t & 1;
        int bi = bb * 32 + og * 2 + nh;
        a += partials[(size_t)bi * 32 + oo * 2];
        q += partials[(size_t)bi * 32 + oo * 2 + 1];
    }
    float mean = a / 65536.0f;
    float var  = q / 65536.0f - mean * mean;
    float scale = gamma[o] * rsqrtf(var + 1e-5f);
    sb[o * 2] = scale;
    sb[o * 2 + 1] = beta[o] - mean * scale;
}

// ---------------- K3c: in-place BN+ReLU on d_out ----------------
__global__ void k3c(float* __restrict__ out, const float* __restrict__ sb) {
    int bi = blockIdx.x;           // 4096 = b*256 + o
    int o = bi & 255;
    float scale = sb[o * 2], bias = sb[o * 2 + 1];
    f32x4* row = (f32x4*)(out + (size_t)bi * N_);
    int u = threadIdx.x;
    #pragma unroll
    for (int k = 0; k < 4; k++) {
        f32x4 v = __builtin_nontemporal_load(&row[u + k * 256]);
        v.x = fmaxf(0.f, fmaf(v.x, scale, bias));
        v.y = fmaxf(0.f, fmaf(v.y, scale, bias));
        v.z = fmaxf(0.f, fmaf(v.z, scale, bias));
        v.w = fmaxf(0.f, fmaf(v.w, scale, bias));
        __builtin_nontemporal_store(v, &row[u + k * 256]);
    }
}

extern "C" void kernel_launch(void* const* d_in, const int* in_sizes, int n_in,
                              void* d_out, int out_size, void* d_ws, size_t ws_size,
                              hipStream_t stream) {
    const float* xyz1  = (const float*)d_in[0];
    const float* xyz2  = (const float*)d_in[1];
    const float* p1    = (const float*)d_in[2];
    const float* p2    = (const float*)d_in[3];
    const float* W     = (const float*)d_in[4];
    const float* gamma = (const float*)d_in[5];
    const float* beta  = (const float*)d_in[6];
    float* out = (float*)d_out;
    char* ws = (char*)d_ws;
    if (ws_size < (size_t)WS_NEED) return;

    int*      idxw     = (int*)(ws + IDXW_OFF);
    uint16_t* ztb      = (uint16_t*)(ws + ZTB_OFF);
    uint16_t* y1       = (uint16_t*)(ws + Y1_OFF);
    float*    partials = (float*)(ws + PART_OFF);
    float*    sb       = (float*)(ws + SB_OFF);
    uint16_t* w1b      = (uint16_t*)(ws + W1B_OFF);
    uint16_t* w2b      = (uint16_t*)(ws + W2B_OFF);

    hipLaunchKernelGGL(k0_prep,    dim3(320),    dim3(256), 0, stream, W, w1b, w2b);
    hipLaunchKernelGGL(k1_threenn, dim3(32, 16), dim3(256), 0, stream, xyz1, xyz2, idxw);
    hipLaunchKernelGGL(k2_z,       dim3(16, 16), dim3(256), 0, stream, p2, w2b, ztb);
    hipLaunchKernelGGL(k2b,        dim3(2048),   dim3(256), 0, stream, p1, w1b, y1);
    hipLaunchKernelGGL(k3a,        dim3(512),    dim3(512), 0, stream, y1, ztb, idxw, out, partials);
    hipLaunchKernelGGL(k3b,        dim3(1),      dim3(256), 0, stream, partials, gamma, beta, sb);
    hipLaunchKernelGGL(k3c,        dim3(4096),   dim3(256), 0, stream, out, sb);
}